// Round 7
// baseline (493.145 us; speedup 1.0000x reference)
//
#include <hip/hip_runtime.h>
#include <math.h>
#include <stdint.h>

#define BATCH 64
#define T 256
#define NF 64
#define H 128
#define H4 512                    // 4*H
#define HP1 129
#define WF_STRIDE (HP1 * H4)      // 66048 floats per feature
#define FEATS (NF * H + H)        // 8320
#define NTH 1024                  // 16 waves

#define RING_HALF 32768           // 32 KB: one K-half of one step (fp8)
// fp8 pack: uint4 index = ((f*16 + wv)*4 + i)*64 + lane   (4 MB total)
#define PACK8_U4 (64 * 16 * 4 * 64)
#define PACK8_BYTES ((size_t)PACK8_U4 * 16u)              // 4 MB
#define HDR_BYTES  (64u * 1024u * 2u)                     // fp16 wx/bias, 128 KB
#define WS_NEED ((size_t)HDR_BYTES + PACK8_BYTES)         // ~4.3 MB

typedef _Float16 half2_t __attribute__((ext_vector_type(2)));
typedef float    vf2     __attribute__((ext_vector_type(2)));

__device__ __forceinline__ float sigmoidf_(float x) {
    return 1.0f / (1.0f + __expf(-x));
}

__device__ __forceinline__ float tanhf_(float x) {
    float ax = fabsf(x);
    float e = __expf(2.0f * ax);              // inf for large ax -> r = 1
    float r = 1.0f - 2.0f / (e + 1.0f);
    return copysignf(r, x);
}

__device__ __forceinline__ float fdot2_(half2_t a, half2_t b, float c) {
#if defined(__has_builtin)
#if __has_builtin(__builtin_amdgcn_fdot2)
    return __builtin_amdgcn_fdot2(a, b, c, false);
#else
    return fmaf((float)a.x, (float)b.x, fmaf((float)a.y, (float)b.y, c));
#endif
#else
    return fmaf((float)a.x, (float)b.x, fmaf((float)a.y, (float)b.y, c));
#endif
}

// decode 2 fp8 bytes -> half2 (fp8 is a subset of fp16; HI must be literal)
template<bool HI>
__device__ __forceinline__ half2_t dec8(unsigned u) {
    vf2 f = __builtin_amdgcn_cvt_pk_f32_fp8(u, HI);
    return (half2_t)__builtin_amdgcn_cvt_pkrtz(f[0], f[1]);
}

// ---- async global->LDS DMA ----
__device__ __forceinline__ void dma16(const void* g, uint32_t lds_byte) {
    __builtin_amdgcn_global_load_lds(
        (const __attribute__((address_space(1))) void*)g,
        (__attribute__((address_space(3))) void*)(uintptr_t)lds_byte,
        16, 0, 0);
}
__device__ __forceinline__ void dma4(const void* g, uint32_t lds_byte) {
    __builtin_amdgcn_global_load_lds(
        (const __attribute__((address_space(1))) void*)g,
        (__attribute__((address_space(3))) void*)(uintptr_t)lds_byte,
        4, 0, 0);
}

#define WAITV(N) do { asm volatile("s_waitcnt vmcnt(" #N ")" ::: "memory"); \
                      __builtin_amdgcn_sched_barrier(0); } while (0)
#define BARRIER() do { asm volatile("s_waitcnt lgkmcnt(0)" ::: "memory"); \
                       __builtin_amdgcn_s_barrier(); \
                       asm volatile("" ::: "memory"); } while (0)

// ===================== repack: W_lin h-rows -> fp8 (x4096), DMA-slice layout ==
// out uint4 idx = ((f*16+wv)*4+i)*64 + l; tid=wv*64+l, kh=tid>>9, c=tid&511;
// dword w byte r of the uint4 <-> k = kh*64 + i*16 + 4w + r,
// value = fp8_e4m3( W_lin[f][1+k][c] * 4096 )   (|w|*4096 <= 363 < 448 = e4m3 max)
__global__ __launch_bounds__(256)
void repack8_kernel(const float* __restrict__ W_lin, uint4* __restrict__ pack) {
    const int lin = blockIdx.x * 256 + threadIdx.x;   // 0..262143
    const int l   = lin & 63;
    const int i   = (lin >> 6) & 3;
    const int wv  = (lin >> 8) & 15;
    const int f   = lin >> 12;
    const int tid = wv * 64 + l;
    const int kh  = tid >> 9;
    const int cc  = tid & 511;
    const int k0  = kh * 64 + i * 16;
    unsigned u[4];
    #pragma unroll
    for (int w = 0; w < 4; ++w) {
        const float* src = W_lin + (size_t)f * WF_STRIDE + (size_t)(1 + k0 + 4 * w) * H4 + cc;
        const float v0 = src[0]      * 4096.0f;
        const float v1 = src[H4]     * 4096.0f;
        const float v2 = src[2 * H4] * 4096.0f;
        const float v3 = src[3 * H4] * 4096.0f;
        unsigned r = 0;
        r = __builtin_amdgcn_cvt_pk_fp8_f32(v0, v1, r, false);
        r = __builtin_amdgcn_cvt_pk_fp8_f32(v2, v3, r, true);
        u[w] = r;
    }
    uint4 o; o.x = u[0]; o.y = u[1]; o.z = u[2]; o.w = u[3];
    pack[lin] = o;
}

// hdr[f*1024 + t] (fp16): t<512 -> W_lin[f][0][t] (x-row); t>=512 -> b_lin[f][t-512]
__global__ __launch_bounds__(256)
void hdr_kernel(const float* __restrict__ W_lin, const float* __restrict__ b_lin,
                _Float16* __restrict__ hdr) {
    const int lin = blockIdx.x * 256 + threadIdx.x;     // 0..65535
    const int f = lin >> 10, t = lin & 1023;
    const float v = (t < 512) ? W_lin[(size_t)f * WF_STRIDE + t]
                              : b_lin[f * H4 + (t & 511)];
    hdr[lin] = (_Float16)v;
}

// ===================== main scan: fp8 + LDS DMA ring, counted vmcnt ==========
// The weight-fetch schedule (mj sequence) is independent of the recurrence, so
// DMA runs a full step ahead through a 3-slot LDS ring (K-half granularity).
// Waves stage & read only their own slices -> weight readiness is per-wave
// vmcnt only. Raw s_barrier + lgkmcnt(0) for phase sync (NO __syncthreads in
// the loop: it would drain vmcnt and kill the pipeline). No compiler vmem in
// the loop (bias/x-row come via fp16 hdr DMA), so vmcnt counts are exact.
// Steady-state FIFO entering step j: [W(j,h0)x2, hdr(j), W(j,h1)x2] = 5.
__global__ __launch_bounds__(NTH, 4)
void lstm_scan_fp8_dma(const float* __restrict__ X,
                       const int* __restrict__ lengths,
                       const float* __restrict__ W_dec,
                       const float* __restrict__ b_dec,
                       const float* __restrict__ W_out,
                       const float* __restrict__ b_out,
                       const uint4* __restrict__ pack,
                       const _Float16* __restrict__ hdr,
                       float* __restrict__ out)
{
    __shared__ __align__(16) char s_wb[3 * RING_HALF];  // 96 KB weight ring
    __shared__ __align__(16) char s_hd[2 * 4096];       // hdr staging (dbuf)
    __shared__ half2_t s_inp2[H / 2];                   // decayed hidden, fp16
    __shared__ float s_ht[NF * H];                      // 32 KB h table (f32)
    __shared__ float s_part[2][H4];
    __shared__ float s_X[4 * T];
    __shared__ float s_wdec[NF];
    __shared__ float s_bdec[NF];
    __shared__ float s_cfin[H];
    __shared__ float s_red[32];

    const int tid  = threadIdx.x;
    const int b    = blockIdx.x;
    const int wv   = tid >> 6;
    const int lane = tid & 63;
    const int kh   = tid >> 9;                // K half (0/1)
    const int c    = tid & 511;               // gate column

    const float* Xb = X + b * 4 * T;
    const int len = lengths[b];

    for (int i = tid; i < NF * H; i += NTH) s_ht[i] = 0.0f;
    for (int i = tid; i < 4 * T; i += NTH) s_X[i] = Xb[i];
    if (tid < NF) { s_wdec[tid] = W_dec[tid]; s_bdec[tid] = b_dec[tid]; }
    if (tid < H) ((_Float16*)s_inp2)[tid] = (_Float16)0.0f;
    __syncthreads();                          // full drain before pipeline starts

    const uint32_t wb0 = (uint32_t)(uintptr_t)s_wb;
    const uint32_t hd0 = (uint32_t)(uintptr_t)s_hd;
    const uint32_t wb_wave = __builtin_amdgcn_readfirstlane(wb0 + wv * 2048);
    const uint32_t hd_wave = __builtin_amdgcn_readfirstlane(hd0 + wv * 256);

    float c_t = 0.0f, acc = 0.0f, cnt = 0.0f;

    // issue DMA for chunk i (i = 2*half + d) of feature mf into ring slot
    #define ISSUE_W(mf, i, slot) do {                                           \
        const uint4* gp = pack + (((size_t)(mf) * 16 + wv) * 4 + (i)) * 64 + lane; \
        dma16(gp, wb_wave + (uint32_t)(slot) * RING_HALF + ((i) & 1) * 1024);   \
    } while (0)

    #define ISSUE_HDR(jj) do {                                                  \
        const int ss = ((jj) < T) ? (jj) : (T - 1);                             \
        const _Float16* gh = hdr + (int)s_X[T + ss] * 1024 + (tid & 1022);      \
        dma4(gh, hd_wave + (((jj) & 1) ? 4096u : 0u));                          \
    } while (0)

    #define DOTU4(W, IB) do {                                                   \
        const half2_t* ip = ((const half2_t*)s_inp2) + (IB);                    \
        union { uint4 u; half2_t h[4]; } I0, I1;                                \
        I0.u = *(const uint4*)(ip);                                             \
        I1.u = *(const uint4*)(ip + 4);                                         \
        a0 = fdot2_(dec8<false>(W.x), I0.h[0], a0);                             \
        a1 = fdot2_(dec8<true >(W.x), I0.h[1], a1);                             \
        a0 = fdot2_(dec8<false>(W.y), I0.h[2], a0);                             \
        a1 = fdot2_(dec8<true >(W.y), I0.h[3], a1);                             \
        a0 = fdot2_(dec8<false>(W.z), I1.h[0], a0);                             \
        a1 = fdot2_(dec8<true >(W.z), I1.h[1], a1);                             \
        a0 = fdot2_(dec8<false>(W.w), I1.h[2], a0);                             \
        a1 = fdot2_(dec8<true >(W.w), I1.h[3], a1);                             \
    } while (0)

    #define HALF_DOT(slot, hh) do {                                             \
        const char* bp = s_wb + (size_t)(slot) * RING_HALF + wv * 2048 + lane * 16; \
        const uint4 W0 = *(const uint4*)(bp);                                   \
        const uint4 W1 = *(const uint4*)(bp + 1024);                            \
        DOTU4(W0, kh * 32 + 16 * (hh));                                         \
        DOTU4(W1, kh * 32 + 16 * (hh) + 8);                                     \
    } while (0)

    // prologue: stage step 0 (h0 -> slot 0, hdr, h1 -> slot 1) = 5 outstanding
    {
        const int m0 = (int)s_X[T];
        ISSUE_W(m0, 0, 0); ISSUE_W(m0, 1, 0);
        ISSUE_HDR(0);
        ISSUE_W(m0, 2, 1); ISSUE_W(m0, 3, 1);
    }

    int r0 = 0;                               // ring slot of (j, h0)
    for (int j = 0; j < len; ++j) {
        const int   mj  = (int)s_X[T + j];
        const float xj  = s_X[2 * T + j];
        const int   jn  = (j + 1 < T) ? (j + 1) : (T - 1);
        const int   mjn = (int)s_X[T + jn];
        int r1 = r0 + 1; if (r1 >= 3) r1 -= 3;
        int r2 = r0 + 2; if (r2 >= 3) r2 -= 3;    // slot for (j+1, h0)

        // issue next-step h0 + hdr (slot r2 was consumed in step j-1)
        ISSUE_W(mjn, 0, r2); ISSUE_W(mjn, 1, r2);
        ISSUE_HDR(j + 1);
        WAITV(5);                              // oldest 3 done: W(j,h0)x2 + hdr(j)

        float a0 = 0.0f, a1 = 0.0f;
        HALF_DOT(r0, 0);
        // ensure r0 ds_reads retired before overwriting r0 with (j+1, h1)
        asm volatile("s_waitcnt lgkmcnt(0)" ::: "memory");
        __builtin_amdgcn_sched_barrier(0);
        ISSUE_W(mjn, 2, r0); ISSUE_W(mjn, 3, r0);
        WAITV(5);                              // oldest 2 done: W(j,h1)x2
        HALF_DOT(r1, 1);

        float a = (a0 + a1) * (1.0f / 4096.0f);
        {
            const float hv = (float)*(const _Float16*)(s_hd
                + ((j & 1) ? 4096 : 0) + wv * 256 + lane * 4 + (tid & 1) * 2);
            a = kh ? (a + hv) : fmaf(xj, hv, a);   // bias / wx*x folded in
        }
        s_part[kh][c] = a;
        BARRIER();  /* partials ready (vmcnt NOT drained: pipeline lives on) */

        if (tid < H) {
            const int h = tid;
            const float gi = s_part[0][h]         + s_part[1][h];
            const float gf = s_part[0][H + h]     + s_part[1][H + h];
            const float go = s_part[0][2 * H + h] + s_part[1][2 * H + h];
            const float gc = s_part[0][3 * H + h] + s_part[1][3 * H + h];
            const float c_cand = sigmoidf_(gf) * c_t + sigmoidf_(gi) * tanhf_(gc);
            const float h_row  = sigmoidf_(go) * tanhf_(c_cand);
            s_ht[mj * H + h] = h_row;
            acc += c_cand;
            cnt += 1.0f;
            const float tj = s_X[j];
            const float tn = (j < T - 1) ? s_X[j + 1] : (tj + 1.0f);
            const bool boundary = (j == len - 1) || (tn != tj);
            if (boundary) { c_t = acc / fmaxf(cnt, 1.0f); acc = 0.0f; cnt = 0.0f; }
            const float dn  = s_X[3 * T + jn];
            const float dmn = fmaf(s_wdec[mjn], dn, s_bdec[mjn]);
            const float den = __expf(-fmaxf(0.0f, dmn));
            const float hv2 = (mjn == mj) ? h_row : s_ht[mjn * H + h];
            ((_Float16*)s_inp2)[h] = (_Float16)(den * hv2);
        }
        BARRIER();  /* s_inp2 + h_t ready */
        r0 = r2;
    }
    #undef HALF_DOT
    #undef DOTU4
    #undef ISSUE_HDR
    #undef ISSUE_W

    asm volatile("s_waitcnt vmcnt(0) lgkmcnt(0)" ::: "memory");
    __syncthreads();

    // ---- epilogue ----
    if (tid < H) s_cfin[tid] = c_t;
    __syncthreads();

    float z0 = 0.0f, z1 = 0.0f;
    for (int i = tid; i < FEATS; i += NTH) {
        const float f = (i < H) ? s_cfin[i] : s_ht[i - H];
        const float2 w = *(const float2*)(W_out + 2 * i);
        z0 = fmaf(f, w.x, z0);
        z1 = fmaf(f, w.y, z1);
    }
    #pragma unroll
    for (int off = 32; off > 0; off >>= 1) {
        z0 += __shfl_down(z0, off, 64);
        z1 += __shfl_down(z1, off, 64);
    }
    const int wave = tid >> 6, lane2 = tid & 63;
    if (lane2 == 0) { s_red[2 * wave] = z0; s_red[2 * wave + 1] = z1; }
    __syncthreads();
    if (tid == 0) {
        float a0 = b_out[0], a1 = b_out[1];
        #pragma unroll
        for (int w = 0; w < 16; ++w) { a0 += s_red[2 * w]; a1 += s_red[2 * w + 1]; }
        const float mx = fmaxf(a0, a1);
        const float e0 = __expf(a0 - mx), e1 = __expf(a1 - mx);
        const float inv = 1.0f / (e0 + e1);
        out[2 * b]     = e0 * inv;
        out[2 * b + 1] = e1 * inv;
    }
}

// ---------------- fp32 fallback (no-workspace path) ----------------
#define NTHREADS 512
__global__ __launch_bounds__(NTHREADS)
void lstm_scan_kernel(const float* __restrict__ X,
                      const int* __restrict__ lengths,
                      const float* __restrict__ W_lin,
                      const float* __restrict__ b_lin,
                      const float* __restrict__ W_dec,
                      const float* __restrict__ b_dec,
                      const float* __restrict__ W_out,
                      const float* __restrict__ b_out,
                      float* __restrict__ out)
{
    __shared__ float s_feats[FEATS];
    __shared__ float s_inp[H];
    __shared__ float s_part[4][H4];
    __shared__ float s_X[4 * T];
    __shared__ float s_wdec[NF];
    __shared__ float s_bdec[NF];
    __shared__ float s_red[16];

    float* s_ct = s_feats;
    float* s_ht = s_feats + H;

    const int tid = threadIdx.x;
    const int b   = blockIdx.x;
    const int g4  = tid & 127;
    const int kq  = tid >> 7;

    const float* Xb = X + b * 4 * T;
    const int len = lengths[b];

    for (int i = tid; i < NF * H; i += NTHREADS) s_ht[i] = 0.0f;
    for (int i = tid; i < 4 * T; i += NTHREADS) s_X[i] = Xb[i];
    if (tid < NF) { s_wdec[tid] = W_dec[tid]; s_bdec[tid] = b_dec[tid]; }
    __syncthreads();

    float c_t = 0.0f, acc = 0.0f, cnt = 0.0f;

    for (int j = 0; j < len; ++j) {
        const int   mj = (int)s_X[T + j];
        const float xj = s_X[2 * T + j];
        const float* Wf = W_lin + mj * WF_STRIDE;

        float bl0, bl1, bl2, bl3;
        if (tid < H) {
            const float dj    = s_X[3 * T + j];
            const float dm    = fmaf(s_wdec[mj], dj, s_bdec[mj]);
            const float decay = __expf(-fmaxf(0.0f, dm));
            s_inp[tid] = decay * s_ht[mj * H + tid];
            const int m4 = mj * H4;
            bl0 = b_lin[m4 + tid];
            bl1 = b_lin[m4 + H + tid];
            bl2 = b_lin[m4 + 2 * H + tid];
            bl3 = b_lin[m4 + 3 * H + tid];
        }
        __syncthreads();

        float4 a4 = make_float4(0.0f, 0.0f, 0.0f, 0.0f);
        {
            const float*  wr  = Wf + (1 + kq * 32) * H4 + 4 * g4;
            const float4* ivp = (const float4*)(s_inp + kq * 32);
            #pragma unroll
            for (int cc = 0; cc < 8; ++cc) {
                const float4 v = ivp[cc];
                const float* wrc = wr + (4 * cc) * H4;
                const float4 w0 = *(const float4*)(wrc);
                const float4 w1 = *(const float4*)(wrc + H4);
                const float4 w2 = *(const float4*)(wrc + 2 * H4);
                const float4 w3 = *(const float4*)(wrc + 3 * H4);
                a4.x = fmaf(v.x, w0.x, a4.x); a4.y = fmaf(v.x, w0.y, a4.y);
                a4.z = fmaf(v.x, w0.z, a4.z); a4.w = fmaf(v.x, w0.w, a4.w);
                a4.x = fmaf(v.y, w1.x, a4.x); a4.y = fmaf(v.y, w1.y, a4.y);
                a4.z = fmaf(v.y, w1.z, a4.z); a4.w = fmaf(v.y, w1.w, a4.w);
                a4.x = fmaf(v.z, w2.x, a4.x); a4.y = fmaf(v.z, w2.y, a4.y);
                a4.z = fmaf(v.z, w2.z, a4.z); a4.w = fmaf(v.z, w2.w, a4.w);
                a4.x = fmaf(v.w, w3.x, a4.x); a4.y = fmaf(v.w, w3.y, a4.y);
                a4.z = fmaf(v.w, w3.z, a4.z); a4.w = fmaf(v.w, w3.w, a4.w);
            }
        }
        if (kq == 0) {
            const float4 w = *(const float4*)(Wf + 4 * g4);
            a4.x = fmaf(xj, w.x, a4.x); a4.y = fmaf(xj, w.y, a4.y);
            a4.z = fmaf(xj, w.z, a4.z); a4.w = fmaf(xj, w.w, a4.w);
        }
        *(float4*)(&s_part[kq][4 * g4]) = a4;
        __syncthreads();

        if (tid < H) {
            const int h = tid;
            const float gi = s_part[0][h]         + s_part[1][h]         + s_part[2][h]         + s_part[3][h]         + bl0;
            const float gf = s_part[0][H + h]     + s_part[1][H + h]     + s_part[2][H + h]     + s_part[3][H + h]     + bl1;
            const float go = s_part[0][2*H + h]   + s_part[1][2*H + h]   + s_part[2][2*H + h]   + s_part[3][2*H + h]   + bl2;
            const float gc = s_part[0][3*H + h]   + s_part[1][3*H + h]   + s_part[2][3*H + h]   + s_part[3][3*H + h]   + bl3;

            const float c_cand = sigmoidf_(gf) * c_t + sigmoidf_(gi) * tanhf_(gc);
            const float h_row  = sigmoidf_(go) * tanhf_(c_cand);
            s_ht[mj * H + h] = h_row;
            acc += c_cand;
            cnt += 1.0f;

            const float tj = s_X[j];
            const float tn = (j < T - 1) ? s_X[j + 1] : (tj + 1.0f);
            const bool boundary = (j == len - 1) || (tn != tj);
            if (boundary) { c_t = acc / fmaxf(cnt, 1.0f); acc = 0.0f; cnt = 0.0f; }
        }
        __syncthreads();
    }

    if (tid < H) s_ct[tid] = c_t;
    __syncthreads();

    float z0 = 0.0f, z1 = 0.0f;
    for (int i = tid; i < FEATS; i += NTHREADS) {
        const float f = s_feats[i];
        const float2 w = *(const float2*)(W_out + 2 * i);
        z0 = fmaf(f, w.x, z0);
        z1 = fmaf(f, w.y, z1);
    }
    #pragma unroll
    for (int off = 32; off > 0; off >>= 1) {
        z0 += __shfl_down(z0, off, 64);
        z1 += __shfl_down(z1, off, 64);
    }
    const int wave = tid >> 6, lane = tid & 63;
    if (lane == 0) { s_red[2 * wave] = z0; s_red[2 * wave + 1] = z1; }
    __syncthreads();
    if (tid == 0) {
        float a0 = b_out[0], a1 = b_out[1];
        #pragma unroll
        for (int w = 0; w < 8; ++w) { a0 += s_red[2 * w]; a1 += s_red[2 * w + 1]; }
        const float mx = fmaxf(a0, a1);
        const float e0 = __expf(a0 - mx), e1 = __expf(a1 - mx);
        const float inv = 1.0f / (e0 + e1);
        out[2 * b]     = e0 * inv;
        out[2 * b + 1] = e1 * inv;
    }
}

extern "C" void kernel_launch(void* const* d_in, const int* in_sizes, int n_in,
                              void* d_out, int out_size, void* d_ws, size_t ws_size,
                              hipStream_t stream) {
    const float* X      = (const float*)d_in[0];
    const int*   lens   = (const int*)d_in[1];
    const float* W_lin  = (const float*)d_in[2];
    const float* b_lin  = (const float*)d_in[3];
    const float* W_dec  = (const float*)d_in[4];
    const float* b_dec  = (const float*)d_in[5];
    const float* W_out  = (const float*)d_in[6];
    const float* b_out  = (const float*)d_in[7];
    float* out = (float*)d_out;

    if (ws_size >= WS_NEED) {
        _Float16* hdr = (_Float16*)d_ws;
        uint4* pack = (uint4*)((char*)d_ws + HDR_BYTES);
        hipLaunchKernelGGL(repack8_kernel, dim3(PACK8_U4 / 256), dim3(256), 0, stream,
                           W_lin, pack);
        hipLaunchKernelGGL(hdr_kernel, dim3(256), dim3(256), 0, stream, W_lin, b_lin, hdr);
        hipLaunchKernelGGL(lstm_scan_fp8_dma, dim3(BATCH), dim3(NTH), 0, stream,
                           X, lens, W_dec, b_dec, W_out, b_out, pack, hdr, out);
    } else {
        hipLaunchKernelGGL(lstm_scan_kernel, dim3(BATCH), dim3(NTHREADS), 0, stream,
                           X, lens, W_lin, b_lin, W_dec, b_dec, W_out, b_out, out);
    }
}